// Round 11
// baseline (60517.285 us; speedup 1.0000x reference)
//
#include <hip/hip_runtime.h>
#include <stdint.h>
#include <math.h>

#define S_ 256
#define B_ 1024
#define E_ 128
#define H_ 128
#define CD_ 16
#define NEGF (-1.0e9f)
#define C_EXPF 10.0f
#define TINYF 1.17549435e-38f

// ---------------- XLA/Eigen-style float32 tanh (rational 13/6) -------------
__device__ __forceinline__ float tanh_ref(float x) {
  const float kClamp = 7.90531110763549805f;
  float xc = fminf(fmaxf(x, -kClamp), kClamp);
  float x2 = __fmul_rn(xc, xc);
  float p = fmaf(x2, -2.76076847742355e-16f, 2.00018790482477e-13f);
  p = fmaf(x2, p, -8.60467152213735e-11f);
  p = fmaf(x2, p, 5.12229709037114e-08f);
  p = fmaf(x2, p, 1.48572235717979e-05f);
  p = fmaf(x2, p, 6.37261928875436e-04f);
  p = fmaf(x2, p, 4.89352455891786e-03f);
  p = __fmul_rn(xc, p);
  float q = fmaf(x2, 1.19825839466702e-06f, 1.18534705686654e-04f);
  q = fmaf(x2, q, 2.26843463243900e-03f);
  q = fmaf(x2, q, 4.89352518554385e-03f);
  return p / q;
}

__device__ __forceinline__ float sigmoid_ref(float x) {
  return 1.0f / (1.0f + expf(-x));
}

// ---------------- threefry2x32 (jax-exact) ---------------------------------
__device__ __forceinline__ uint32_t rotl32(uint32_t v, uint32_t r) {
  return (v << r) | (v >> (32u - r));
}
__device__ __forceinline__ void threefry2x32(uint32_t k0, uint32_t k1,
                                             uint32_t x0, uint32_t x1,
                                             uint32_t& o0, uint32_t& o1) {
  const uint32_t k2 = k0 ^ k1 ^ 0x1BD11BDAu;
  x0 += k0; x1 += k1;
  x0 += x1; x1 = rotl32(x1, 13); x1 ^= x0;
  x0 += x1; x1 = rotl32(x1, 15); x1 ^= x0;
  x0 += x1; x1 = rotl32(x1, 26); x1 ^= x0;
  x0 += x1; x1 = rotl32(x1,  6); x1 ^= x0;
  x0 += k1; x1 += k2 + 1u;
  x0 += x1; x1 = rotl32(x1, 17); x1 ^= x0;
  x0 += x1; x1 = rotl32(x1, 29); x1 ^= x0;
  x0 += x1; x1 = rotl32(x1, 16); x1 ^= x0;
  x0 += x1; x1 = rotl32(x1, 24); x1 ^= x0;
  x0 += k2; x1 += k0 + 2u;
  x0 += x1; x1 = rotl32(x1, 13); x1 ^= x0;
  x0 += x1; x1 = rotl32(x1, 15); x1 ^= x0;
  x0 += x1; x1 = rotl32(x1, 26); x1 ^= x0;
  x0 += x1; x1 = rotl32(x1,  6); x1 ^= x0;
  x0 += k0; x1 += k1 + 3u;
  x0 += x1; x1 = rotl32(x1, 17); x1 ^= x0;
  x0 += x1; x1 = rotl32(x1, 29); x1 ^= x0;
  x0 += x1; x1 = rotl32(x1, 16); x1 ^= x0;
  x0 += x1; x1 = rotl32(x1, 24); x1 ^= x0;
  x0 += k1; x1 += k2 + 4u;
  x0 += x1; x1 = rotl32(x1, 13); x1 ^= x0;
  x0 += x1; x1 = rotl32(x1, 15); x1 ^= x0;
  x0 += x1; x1 = rotl32(x1, 26); x1 ^= x0;
  x0 += x1; x1 = rotl32(x1,  6); x1 ^= x0;
  x0 += k2; x1 += k0 + 5u;
  o0 = x0; o1 = x1;
}

__device__ __forceinline__ float gumbel_from_bits(uint32_t bits) {
  float f = __uint_as_float((bits >> 9) | 0x3f800000u) - 1.0f;
  f = __fadd_rn(f, TINYF);
  f = fmaxf(f, TINYF);
  return -logf(-logf(f));
}

// ---------------- wave helpers ---------------------------------------------
__device__ __forceinline__ float wave_max(float v) {
  for (int off = 32; off > 0; off >>= 1) v = fmaxf(v, __shfl_xor(v, off));
  return v;
}
__device__ __forceinline__ float wave_sum(float v) {
  for (int off = 32; off > 0; off >>= 1) v = __fadd_rn(v, __shfl_xor(v, off));
  return v;
}

// 4 score terms, h ascending — exact order
__device__ __forceinline__ void acc4(float& a, const float* sv, const float* sq,
                                     int h, float4 e) {
  a = fmaf(sv[h + 0], tanh_ref(__fadd_rn(sq[h + 0], e.x)), a);
  a = fmaf(sv[h + 1], tanh_ref(__fadd_rn(sq[h + 1], e.y)), a);
  a = fmaf(sv[h + 2], tanh_ref(__fadd_rn(sq[h + 2], e.z)), a);
  a = fmaf(sv[h + 3], tanh_ref(__fadd_rn(sq[h + 3], e.w)), a);
}

// score over a REGISTER-resident e-row (32 float4, static idx) — R8-proven
__device__ __forceinline__ float score_reg(const float4* ereg,
                                           const float* sv, const float* sq) {
  float a = 0.0f;
#pragma unroll
  for (int k4 = 0; k4 < 32; ++k4) acc4(a, sv, sq, k4 * 4, ereg[k4]);
  return a;
}

// ---------------- precompute e_g / e_p: layout [B,S,H] ---------------------
__global__ __launch_bounds__(256) void precompute_e(
    const float* __restrict__ context,  // [S,B,H]
    const float* __restrict__ Wr_g, const float* __restrict__ br_g,
    const float* __restrict__ Wr_p, const float* __restrict__ br_p,
    float* __restrict__ e_g, float* __restrict__ e_p) {
  const int b = blockIdx.x;
  const int s0 = blockIdx.y * 64;
  const int tid = threadIdx.x;
  __shared__ float ctx[64 * 129];
  for (int i = tid; i < 64 * H_; i += 256) {
    const int sl = i >> 7, h = i & 127;
    ctx[sl * 129 + h] = context[((size_t)(s0 + sl) * B_ + b) * H_ + h];
  }
  __syncthreads();
  const int sl = tid & 63, og = tid >> 6;
  for (int o = og; o < H_; o += 4) {
    const float* __restrict__ wg = Wr_g + (size_t)o * H_;
    const float* __restrict__ wp = Wr_p + (size_t)o * H_;
    float ag = 0.0f, ap = 0.0f;
    for (int h = 0; h < H_; ++h) {
      const float cv = ctx[sl * 129 + h];
      ag = fmaf(wg[h], cv, ag);
      ap = fmaf(wp[h], cv, ap);
    }
    ag = __fadd_rn(ag, br_g[o]);
    ap = __fadd_rn(ap, br_p[o]);
    const size_t off = ((size_t)b * S_ + (s0 + sl)) * H_ + o;  // [b][s][h]
    e_g[off] = ag;
    e_p[off] = ap;
  }
}

// ---------------- main: 512 threads/row, wave-specialized by score ---------
// A threads (tid<256): full e_g row s=tid in registers; own glimpse score,
// softmax-g, gather. B threads (tid>=256): full e_p row s=tid-256; own
// pointer score, softmax-p, sampling. ctx slice LDS-resident.
__global__ __launch_bounds__(512, 2) void decoder_main(
    const float* __restrict__ dec0, const float* __restrict__ emb,
    const float* __restrict__ h0, const float* __restrict__ c0,
    const float* __restrict__ context, const float* __restrict__ capacity,
    const float* __restrict__ weights,
    const float* __restrict__ W_ih, const float* __restrict__ b_ih,
    const float* __restrict__ W_hh, const float* __restrict__ b_hh,
    const float* __restrict__ W_cap, const float* __restrict__ b_cap,
    const float* __restrict__ W_proj, const float* __restrict__ b_proj,
    const float* __restrict__ Wq_g, const float* __restrict__ bq_g,
    const float* __restrict__ v_g,
    const float* __restrict__ Wq_p, const float* __restrict__ bq_p,
    const float* __restrict__ v_p,
    const float* __restrict__ e_g, const float* __restrict__ e_p,
    float* __restrict__ out_probs, float* __restrict__ out_sel) {
  const int b = blockIdx.x;
  const int tid = threadIdx.x;
  const int lane = tid & 63;
  const int wv = tid >> 6;        // 0..7
  const int isB = tid >> 8;       // 0 = A (e_g), 1 = B (e_p)
  const int s_own = tid & 255;    // row this thread owns for its score

  __shared__ float lds_ctx[S_ * H_];  // 128 KB: ctx slice [s][h]
  __shared__ float sh_h[H_], sh_c[H_], sh_dec[E_];
  __shared__ float sh_pq[H_], sh_q[H_], sh_gl2[H_];
  __shared__ float sh_gates[2 * S_];
  __shared__ float sh_gw[S_], sh_w[S_];
  __shared__ float sh_cap[CD_], sh_vg[H_], sh_vp[H_];
  __shared__ uint32_t sh_sel[S_ / 32], sh_comb[S_ / 32];
  __shared__ float sh_red[8];
  __shared__ int sh_redi[8];
  __shared__ float sh_rem;
  __shared__ int sh_idx;

  if (tid < H_) {
    sh_h[tid] = h0[(size_t)b * H_ + tid];
    sh_c[tid] = c0[(size_t)b * H_ + tid];
    sh_dec[tid] = dec0[(size_t)b * E_ + tid];
    sh_vg[tid] = v_g[tid];
    sh_vp[tid] = v_p[tid];
  }
  if (tid < CD_) {
    sh_cap[tid] = __fadd_rn(__fmul_rn(capacity[b], W_cap[tid]), b_cap[tid]);
  }
  if (tid < S_ / 32) sh_sel[tid] = 0u;
  if (tid < S_) sh_w[tid] = weights[(size_t)b * S_ + tid];
  if (tid == 0) sh_rem = capacity[b];

  // one-time: ctx slice -> LDS ([s][h], coalesced float4 loads)
  for (int i = tid; i < S_ * H_ / 4; i += 512) {
    const int s = i >> 5, h4 = i & 31;
    ((float4*)lds_ctx)[i] =
        *(const float4*)(context + ((size_t)s * B_ + b) * H_ + h4 * 4);
  }

  // one-time: this thread's FULL e row -> registers (A: e_g, B: e_p)
  const float4* __restrict__ erow4 = (const float4*)(
      (isB ? e_p : e_g) + ((size_t)b * S_ + s_own) * H_);
  float4 er[32];
#pragma unroll
  for (int j = 0; j < 32; ++j) er[j] = erow4[j];
  __syncthreads();

  for (int t = 0; t < S_; ++t) {
    // (1) LSTM gates: one row per thread (512 rows), k ascending
    {
      const int j = tid;
      const float4* wi4 = (const float4*)(W_ih + (size_t)j * E_);
      const float4* wh4 = (const float4*)(W_hh + (size_t)j * H_);
      float a1 = 0.0f, a2 = 0.0f;
#pragma unroll 4
      for (int k4 = 0; k4 < E_ / 4; ++k4) {
        const float4 w = wi4[k4];
        a1 = fmaf(sh_dec[k4 * 4 + 0], w.x, a1);
        a1 = fmaf(sh_dec[k4 * 4 + 1], w.y, a1);
        a1 = fmaf(sh_dec[k4 * 4 + 2], w.z, a1);
        a1 = fmaf(sh_dec[k4 * 4 + 3], w.w, a1);
      }
#pragma unroll 4
      for (int k4 = 0; k4 < H_ / 4; ++k4) {
        const float4 w = wh4[k4];
        a2 = fmaf(sh_h[k4 * 4 + 0], w.x, a2);
        a2 = fmaf(sh_h[k4 * 4 + 1], w.y, a2);
        a2 = fmaf(sh_h[k4 * 4 + 2], w.z, a2);
        a2 = fmaf(sh_h[k4 * 4 + 3], w.w, a2);
      }
      sh_gates[j] = __fadd_rn(__fadd_rn(__fadd_rn(a1, b_ih[j]), a2), b_hh[j]);
    }
    __syncthreads();
    // (2) cell update
    if (tid < H_) {
      const float gi = sigmoid_ref(sh_gates[tid]);
      const float gf = sigmoid_ref(sh_gates[H_ + tid]);
      const float gg = tanh_ref(sh_gates[2 * H_ + tid]);
      const float go = sigmoid_ref(sh_gates[3 * H_ + tid]);
      const float cn = __fadd_rn(__fmul_rn(gf, sh_c[tid]), __fmul_rn(gi, gg));
      sh_c[tid] = cn;
      sh_h[tid] = __fmul_rn(go, tanh_ref(cn));
    }
    __syncthreads();
    // (3) pq = [h,cap].W_proj^T + b ; qg = pq.Wq_g^T + bq_g
    if (tid < H_) {
      const float4* wp4 = (const float4*)(W_proj + (size_t)tid * (H_ + CD_));
      float a = 0.0f;
#pragma unroll 4
      for (int k4 = 0; k4 < H_ / 4; ++k4) {
        const float4 w = wp4[k4];
        a = fmaf(sh_h[k4 * 4 + 0], w.x, a);
        a = fmaf(sh_h[k4 * 4 + 1], w.y, a);
        a = fmaf(sh_h[k4 * 4 + 2], w.z, a);
        a = fmaf(sh_h[k4 * 4 + 3], w.w, a);
      }
#pragma unroll
      for (int k4 = 0; k4 < CD_ / 4; ++k4) {
        const float4 w = wp4[H_ / 4 + k4];
        a = fmaf(sh_cap[k4 * 4 + 0], w.x, a);
        a = fmaf(sh_cap[k4 * 4 + 1], w.y, a);
        a = fmaf(sh_cap[k4 * 4 + 2], w.z, a);
        a = fmaf(sh_cap[k4 * 4 + 3], w.w, a);
      }
      sh_pq[tid] = __fadd_rn(a, b_proj[tid]);
    }
    __syncthreads();
    if (tid < H_) {
      const float4* wq4 = (const float4*)(Wq_g + (size_t)tid * H_);
      float a = 0.0f;
#pragma unroll 4
      for (int k4 = 0; k4 < H_ / 4; ++k4) {
        const float4 w = wq4[k4];
        a = fmaf(sh_pq[k4 * 4 + 0], w.x, a);
        a = fmaf(sh_pq[k4 * 4 + 1], w.y, a);
        a = fmaf(sh_pq[k4 * 4 + 2], w.z, a);
        a = fmaf(sh_pq[k4 * 4 + 3], w.w, a);
      }
      sh_q[tid] = __fadd_rn(a, bq_g[tid]);
    }
    __syncthreads();
    // (4) glimpse scores: A threads, full R8 chain + softmax-g (waves 0-3)
    if (!isB) {
      const float gl = score_reg(er, sh_vg, sh_q);
      const float wm = wave_max(gl);
      if (lane == 0) sh_red[wv] = wm;
      __syncthreads();
      const float gmax = fmaxf(fmaxf(sh_red[0], sh_red[1]), fmaxf(sh_red[2], sh_red[3]));
      const float ge = expf(__fsub_rn(gl, gmax));
      const float wsm = wave_sum(ge);
      if (lane == 0) sh_red[4 + wv] = wsm;
      __syncthreads();
      const float gtot = __fadd_rn(__fadd_rn(sh_red[4], sh_red[5]), __fadd_rn(sh_red[6], sh_red[7]));
      sh_gw[s_own] = ge / gtot;
    } else {
      __syncthreads();
      __syncthreads();
    }
    __syncthreads();
    // (5) g_l = sum_s ctx[b,h,s]*gw[s] — A threads, validated 2x128 pattern
    if (!isB) {
      const int hh = tid & 127, half = tid >> 7;
      const float* __restrict__ cl = lds_ctx + (size_t)(half * 128) * H_ + hh;
      const float* __restrict__ gw = sh_gw + half * 128;
      float acc = 0.0f;
#pragma unroll 8
      for (int s = 0; s < 128; ++s) acc = fmaf(cl[(size_t)s * H_], gw[s], acc);
      sh_gates[tid] = acc;  // scratch partials
    }
    __syncthreads();
    if (tid < H_) sh_gl2[tid] = __fadd_rn(sh_gates[tid], sh_gates[tid + 128]);
    __syncthreads();
    // (6) fpq = [g_l,cap].W_proj^T + b ; qp = fpq.Wq_p^T + bq_p
    if (tid < H_) {
      const float4* wp4 = (const float4*)(W_proj + (size_t)tid * (H_ + CD_));
      float a = 0.0f;
#pragma unroll 4
      for (int k4 = 0; k4 < H_ / 4; ++k4) {
        const float4 w = wp4[k4];
        a = fmaf(sh_gl2[k4 * 4 + 0], w.x, a);
        a = fmaf(sh_gl2[k4 * 4 + 1], w.y, a);
        a = fmaf(sh_gl2[k4 * 4 + 2], w.z, a);
        a = fmaf(sh_gl2[k4 * 4 + 3], w.w, a);
      }
#pragma unroll
      for (int k4 = 0; k4 < CD_ / 4; ++k4) {
        const float4 w = wp4[H_ / 4 + k4];
        a = fmaf(sh_cap[k4 * 4 + 0], w.x, a);
        a = fmaf(sh_cap[k4 * 4 + 1], w.y, a);
        a = fmaf(sh_cap[k4 * 4 + 2], w.z, a);
        a = fmaf(sh_cap[k4 * 4 + 3], w.w, a);
      }
      sh_pq[tid] = __fadd_rn(a, b_proj[tid]);
    }
    __syncthreads();
    if (tid < H_) {
      const float4* wq4 = (const float4*)(Wq_p + (size_t)tid * H_);
      float a = 0.0f;
#pragma unroll 4
      for (int k4 = 0; k4 < H_ / 4; ++k4) {
        const float4 w = wq4[k4];
        a = fmaf(sh_pq[k4 * 4 + 0], w.x, a);
        a = fmaf(sh_pq[k4 * 4 + 1], w.y, a);
        a = fmaf(sh_pq[k4 * 4 + 2], w.z, a);
        a = fmaf(sh_pq[k4 * 4 + 3], w.w, a);
      }
      sh_q[tid] = __fadd_rn(a, bq_p[tid]);
    }
    __syncthreads();
    // (7) pointer scores: B threads, full R8 chain; mask/softmax/sample
    if (isB) {
      const float a = score_reg(er, sh_vp, sh_q);
      const float logit = __fmul_rn(C_EXPF, tanh_ref(a));
      const bool selb = (sh_sel[s_own >> 5] >> (s_own & 31)) & 1u;
      const bool wok = (sh_w[s_own] <= sh_rem);
      const bool comb = (!selb) && wok;
      const unsigned long long bal = __ballot(comb);
      if (lane == 0) {
        sh_comb[2 * (wv - 4)] = (uint32_t)bal;
        sh_comb[2 * (wv - 4) + 1] = (uint32_t)(bal >> 32);
      }
      const float ml = comb ? logit : NEGF;
      const float wm = wave_max(ml);
      if (lane == 0) sh_red[wv - 4] = wm;
      __syncthreads();
      const float pmax = fmaxf(fmaxf(sh_red[0], sh_red[1]), fmaxf(sh_red[2], sh_red[3]));
      const float pe = expf(__fsub_rn(ml, pmax));
      const float wsm = wave_sum(pe);
      if (lane == 0) sh_red[4 + (wv - 4)] = wsm;
      __syncthreads();
      const float ptot = __fadd_rn(__fadd_rn(sh_red[4], sh_red[5]), __fadd_rn(sh_red[6], sh_red[7]));
      const float p = pe / ptot;
      __builtin_nontemporal_store(p, &out_probs[((size_t)t * B_ + b) * S_ + s_own]);
      uint32_t kk0, kk1;
      threefry2x32(0u, 42u, 0u, (uint32_t)t, kk0, kk1);
      uint32_t bits;
      { uint32_t o0, o1; threefry2x32(kk0, kk1, 0u, (uint32_t)(b * S_ + s_own), o0, o1); bits = o0 ^ o1; }
      const float z = __fadd_rn(logf(__fadd_rn(p, 1e-30f)), gumbel_from_bits(bits));
      // (8) argmax within wave (first max wins)
      float bz = z; int bi = s_own;
      for (int off = 32; off > 0; off >>= 1) {
        const float oz = __shfl_xor(bz, off);
        const int oi = __shfl_xor(bi, off);
        if (oz > bz || (oz == bz && oi < bi)) { bz = oz; bi = oi; }
      }
      if (lane == 0) { sh_red[wv - 4] = bz; sh_redi[wv - 4] = bi; }
    } else {
      __syncthreads();
      __syncthreads();
    }
    __syncthreads();
    if (tid == 0) {
      float bz = sh_red[0]; int bi = sh_redi[0];
      for (int w = 1; w < 4; ++w)
        if (sh_red[w] > bz || (sh_red[w] == bz && sh_redi[w] < bi)) { bz = sh_red[w]; bi = sh_redi[w]; }
      sh_idx = bi;
      __builtin_nontemporal_store((float)bi, &out_sel[(size_t)t * B_ + b]);
      const bool valid = (sh_comb[bi >> 5] >> (bi & 31)) & 1u;
      sh_rem = __fsub_rn(sh_rem, __fmul_rn(sh_w[bi], valid ? 1.0f : 0.0f));
      sh_sel[bi >> 5] |= (1u << (bi & 31));
    }
    __syncthreads();
    if (tid < E_) sh_dec[tid] = emb[((size_t)sh_idx * B_ + b) * E_ + tid];
    __syncthreads();
  }
}

extern "C" void kernel_launch(void* const* d_in, const int* in_sizes, int n_in,
                              void* d_out, int out_size, void* d_ws, size_t ws_size,
                              hipStream_t stream) {
  const float* dec0 = (const float*)d_in[0];
  const float* emb = (const float*)d_in[1];
  const float* h0 = (const float*)d_in[2];
  const float* c0 = (const float*)d_in[3];
  const float* context = (const float*)d_in[4];
  const float* capacity = (const float*)d_in[5];
  const float* weights = (const float*)d_in[7];
  const float* W_ih = (const float*)d_in[8];
  const float* b_ih = (const float*)d_in[9];
  const float* W_hh = (const float*)d_in[10];
  const float* b_hh = (const float*)d_in[11];
  const float* W_cap = (const float*)d_in[12];
  const float* b_cap = (const float*)d_in[13];
  const float* W_proj = (const float*)d_in[14];
  const float* b_proj = (const float*)d_in[15];
  const float* Wq_g = (const float*)d_in[16];
  const float* bq_g = (const float*)d_in[17];
  const float* Wr_g = (const float*)d_in[18];
  const float* br_g = (const float*)d_in[19];
  const float* v_g = (const float*)d_in[20];
  const float* Wq_p = (const float*)d_in[21];
  const float* bq_p = (const float*)d_in[22];
  const float* Wr_p = (const float*)d_in[23];
  const float* br_p = (const float*)d_in[24];
  const float* v_p = (const float*)d_in[25];

  float* e_g = (float*)d_ws;                          // [B,S,H] = 128 MB
  float* e_p = e_g + (size_t)B_ * S_ * H_;            // [B,S,H] = 128 MB
  float* out_probs = (float*)d_out;                   // [S,B,S]
  float* out_sel = out_probs + (size_t)S_ * B_ * S_;  // [S,B]

  precompute_e<<<dim3(B_, S_ / 64), 256, 0, stream>>>(context, Wr_g, br_g, Wr_p,
                                                      br_p, e_g, e_p);
  decoder_main<<<dim3(B_), 512, 0, stream>>>(
      dec0, emb, h0, c0, context, capacity, weights, W_ih, b_ih, W_hh,
      b_hh, W_cap, b_cap, W_proj, b_proj, Wq_g, bq_g, v_g, Wq_p, bq_p, v_p,
      e_g, e_p, out_probs, out_sel);
}

// Round 12
// 48676.413 us; speedup vs baseline: 1.2433x; 1.2433x over previous
//
#include <hip/hip_runtime.h>
#include <stdint.h>
#include <math.h>

#define S_ 256
#define B_ 1024
#define E_ 128
#define H_ 128
#define CD_ 16
#define NEGF (-1.0e9f)
#define C_EXPF 10.0f
#define TINYF 1.17549435e-38f
#define EGP 129  // e_g LDS row pitch (floats): bank (lane+h)%32 -> 2-way, free

// ---------------- XLA/Eigen-style float32 tanh (rational 13/6) -------------
__device__ __forceinline__ float tanh_ref(float x) {
  const float kClamp = 7.90531110763549805f;
  float xc = fminf(fmaxf(x, -kClamp), kClamp);
  float x2 = __fmul_rn(xc, xc);
  float p = fmaf(x2, -2.76076847742355e-16f, 2.00018790482477e-13f);
  p = fmaf(x2, p, -8.60467152213735e-11f);
  p = fmaf(x2, p, 5.12229709037114e-08f);
  p = fmaf(x2, p, 1.48572235717979e-05f);
  p = fmaf(x2, p, 6.37261928875436e-04f);
  p = fmaf(x2, p, 4.89352455891786e-03f);
  p = __fmul_rn(xc, p);
  float q = fmaf(x2, 1.19825839466702e-06f, 1.18534705686654e-04f);
  q = fmaf(x2, q, 2.26843463243900e-03f);
  q = fmaf(x2, q, 4.89352518554385e-03f);
  return p / q;
}

__device__ __forceinline__ float sigmoid_ref(float x) {
  return 1.0f / (1.0f + expf(-x));
}

// ---------------- threefry2x32 (jax-exact) ---------------------------------
__device__ __forceinline__ uint32_t rotl32(uint32_t v, uint32_t r) {
  return (v << r) | (v >> (32u - r));
}
__device__ __forceinline__ void threefry2x32(uint32_t k0, uint32_t k1,
                                             uint32_t x0, uint32_t x1,
                                             uint32_t& o0, uint32_t& o1) {
  const uint32_t k2 = k0 ^ k1 ^ 0x1BD11BDAu;
  x0 += k0; x1 += k1;
  x0 += x1; x1 = rotl32(x1, 13); x1 ^= x0;
  x0 += x1; x1 = rotl32(x1, 15); x1 ^= x0;
  x0 += x1; x1 = rotl32(x1, 26); x1 ^= x0;
  x0 += x1; x1 = rotl32(x1,  6); x1 ^= x0;
  x0 += k1; x1 += k2 + 1u;
  x0 += x1; x1 = rotl32(x1, 17); x1 ^= x0;
  x0 += x1; x1 = rotl32(x1, 29); x1 ^= x0;
  x0 += x1; x1 = rotl32(x1, 16); x1 ^= x0;
  x0 += x1; x1 = rotl32(x1, 24); x1 ^= x0;
  x0 += k2; x1 += k0 + 2u;
  x0 += x1; x1 = rotl32(x1, 13); x1 ^= x0;
  x0 += x1; x1 = rotl32(x1, 15); x1 ^= x0;
  x0 += x1; x1 = rotl32(x1, 26); x1 ^= x0;
  x0 += x1; x1 = rotl32(x1,  6); x1 ^= x0;
  x0 += k0; x1 += k1 + 3u;
  x0 += x1; x1 = rotl32(x1, 17); x1 ^= x0;
  x0 += x1; x1 = rotl32(x1, 29); x1 ^= x0;
  x0 += x1; x1 = rotl32(x1, 16); x1 ^= x0;
  x0 += x1; x1 = rotl32(x1, 24); x1 ^= x0;
  x0 += k1; x1 += k2 + 4u;
  x0 += x1; x1 = rotl32(x1, 13); x1 ^= x0;
  x0 += x1; x1 = rotl32(x1, 15); x1 ^= x0;
  x0 += x1; x1 = rotl32(x1, 26); x1 ^= x0;
  x0 += x1; x1 = rotl32(x1,  6); x1 ^= x0;
  x0 += k2; x1 += k0 + 5u;
  o0 = x0; o1 = x1;
}

__device__ __forceinline__ float gumbel_from_bits(uint32_t bits) {
  float f = __uint_as_float((bits >> 9) | 0x3f800000u) - 1.0f;
  f = __fadd_rn(f, TINYF);
  f = fmaxf(f, TINYF);
  return -logf(-logf(f));
}

// ---------------- wave helpers ---------------------------------------------
__device__ __forceinline__ float wave_max(float v) {
  for (int off = 32; off > 0; off >>= 1) v = fmaxf(v, __shfl_xor(v, off));
  return v;
}
__device__ __forceinline__ float wave_sum(float v) {
  for (int off = 32; off > 0; off >>= 1) v = __fadd_rn(v, __shfl_xor(v, off));
  return v;
}

// 4 score terms, h ascending — exact order
__device__ __forceinline__ void acc4(float& a, const float* sv, const float* sq,
                                     int h, float4 e) {
  a = fmaf(sv[h + 0], tanh_ref(__fadd_rn(sq[h + 0], e.x)), a);
  a = fmaf(sv[h + 1], tanh_ref(__fadd_rn(sq[h + 1], e.y)), a);
  a = fmaf(sv[h + 2], tanh_ref(__fadd_rn(sq[h + 2], e.z)), a);
  a = fmaf(sv[h + 3], tanh_ref(__fadd_rn(sq[h + 3], e.w)), a);
}

// score over a REGISTER-resident e-row (32 float4, static idx) — R8-proven
__device__ __forceinline__ float score_reg(const float4* ereg,
                                           const float* sv, const float* sq) {
  float a = 0.0f;
#pragma unroll
  for (int k4 = 0; k4 < 32; ++k4) acc4(a, sv, sq, k4 * 4, ereg[k4]);
  return a;
}

// score over an LDS-resident e-row (pitch EGP), h ascending — same chain
__device__ __forceinline__ float score_lds(const float* __restrict__ elds,
                                           const float* sv, const float* sq) {
  float a = 0.0f;
#pragma unroll 8
  for (int h = 0; h < H_; ++h)
    a = fmaf(sv[h], tanh_ref(__fadd_rn(sq[h], elds[h])), a);
  return a;
}

// ---------------- precompute e_g / e_p: layout [B,S,H] ---------------------
__global__ __launch_bounds__(256) void precompute_e(
    const float* __restrict__ context,  // [S,B,H]
    const float* __restrict__ Wr_g, const float* __restrict__ br_g,
    const float* __restrict__ Wr_p, const float* __restrict__ br_p,
    float* __restrict__ e_g, float* __restrict__ e_p) {
  const int b = blockIdx.x;
  const int s0 = blockIdx.y * 64;
  const int tid = threadIdx.x;
  __shared__ float ctx[64 * 129];
  for (int i = tid; i < 64 * H_; i += 256) {
    const int sl = i >> 7, h = i & 127;
    ctx[sl * 129 + h] = context[((size_t)(s0 + sl) * B_ + b) * H_ + h];
  }
  __syncthreads();
  const int sl = tid & 63, og = tid >> 6;
  for (int o = og; o < H_; o += 4) {
    const float* __restrict__ wg = Wr_g + (size_t)o * H_;
    const float* __restrict__ wp = Wr_p + (size_t)o * H_;
    float ag = 0.0f, ap = 0.0f;
    for (int h = 0; h < H_; ++h) {
      const float cv = ctx[sl * 129 + h];
      ag = fmaf(wg[h], cv, ag);
      ap = fmaf(wp[h], cv, ap);
    }
    ag = __fadd_rn(ag, br_g[o]);
    ap = __fadd_rn(ap, br_p[o]);
    const size_t off = ((size_t)b * S_ + (s0 + sl)) * H_ + o;  // [b][s][h]
    e_g[off] = ag;
    e_p[off] = ap;
  }
}

// ---------------- main: one block per batch row, 256 steps -----------------
// e_g -> LDS (pitch-129, conflict-free); e_p -> registers (128 VGPR);
// ctx -> streamed from L3 per step. ~128 VGPRs freed for tanh pipelining.
__global__ __launch_bounds__(256, 1) void decoder_main(
    const float* __restrict__ dec0, const float* __restrict__ emb,
    const float* __restrict__ h0, const float* __restrict__ c0,
    const float* __restrict__ context, const float* __restrict__ capacity,
    const float* __restrict__ weights,
    const float* __restrict__ W_ih, const float* __restrict__ b_ih,
    const float* __restrict__ W_hh, const float* __restrict__ b_hh,
    const float* __restrict__ W_cap, const float* __restrict__ b_cap,
    const float* __restrict__ W_proj, const float* __restrict__ b_proj,
    const float* __restrict__ Wq_g, const float* __restrict__ bq_g,
    const float* __restrict__ v_g,
    const float* __restrict__ Wq_p, const float* __restrict__ bq_p,
    const float* __restrict__ v_p,
    const float* __restrict__ e_g, const float* __restrict__ e_p,
    float* __restrict__ out_probs, float* __restrict__ out_sel) {
  const int b = blockIdx.x;
  const int tid = threadIdx.x;
  const int lane = tid & 63;
  const int wv = tid >> 6;

  __shared__ float lds_eg[S_ * EGP];  // 132 KB: e_g rows, pitch 129
  __shared__ float sh_h[H_], sh_c[H_], sh_dec[E_];
  __shared__ float sh_pq[H_], sh_q[H_], sh_gl2[H_];
  __shared__ float sh_gates[4 * H_];
  __shared__ float sh_gw[S_], sh_w[S_];
  __shared__ float sh_cap[CD_], sh_vg[H_], sh_vp[H_];
  __shared__ uint32_t sh_sel[S_ / 32], sh_comb[S_ / 32];
  __shared__ float sh_red[8];
  __shared__ int sh_redi[8];
  __shared__ float sh_rem;
  __shared__ int sh_idx;

  if (tid < H_) {
    sh_h[tid] = h0[(size_t)b * H_ + tid];
    sh_c[tid] = c0[(size_t)b * H_ + tid];
    sh_dec[tid] = dec0[(size_t)b * E_ + tid];
    sh_vg[tid] = v_g[tid];
    sh_vp[tid] = v_p[tid];
  }
  if (tid < CD_) {
    sh_cap[tid] = __fadd_rn(__fmul_rn(capacity[b], W_cap[tid]), b_cap[tid]);
  }
  if (tid < S_ / 32) sh_sel[tid] = 0u;
  sh_w[tid] = weights[(size_t)b * S_ + tid];
  if (tid == 0) sh_rem = capacity[b];

  // one-time: e_g block-slice -> LDS (coalesced float4 global reads,
  // scalar ds_writes into the padded pitch)
  {
    const float4* __restrict__ egb4 = (const float4*)(e_g + (size_t)b * S_ * H_);
    for (int i4 = tid; i4 < S_ * H_ / 4; i4 += 256) {
      const int s = i4 >> 5, h4 = i4 & 31;
      const float4 v = egb4[i4];
      float* dst = lds_eg + s * EGP + h4 * 4;
      dst[0] = v.x; dst[1] = v.y; dst[2] = v.z; dst[3] = v.w;
    }
  }

  // one-time: this thread's e_p row (s == tid) -> registers for all steps
  const float4* __restrict__ ep_row4 = (const float4*)(e_p + ((size_t)b * S_ + tid) * H_);
  float4 ep[32];
#pragma unroll
  for (int k4 = 0; k4 < 32; ++k4) ep[k4] = ep_row4[k4];
  __syncthreads();

  const float* __restrict__ eg_lds = lds_eg + tid * EGP;

  for (int t = 0; t < S_; ++t) {
    // (1) LSTM gates, float4-vectorized rows, k ascending
#pragma unroll
    for (int jj = 0; jj < 2; ++jj) {
      const int j = tid + jj * 256;
      const float4* wi4 = (const float4*)(W_ih + (size_t)j * E_);
      const float4* wh4 = (const float4*)(W_hh + (size_t)j * H_);
      float a1 = 0.0f, a2 = 0.0f;
#pragma unroll 4
      for (int k4 = 0; k4 < E_ / 4; ++k4) {
        const float4 w = wi4[k4];
        a1 = fmaf(sh_dec[k4 * 4 + 0], w.x, a1);
        a1 = fmaf(sh_dec[k4 * 4 + 1], w.y, a1);
        a1 = fmaf(sh_dec[k4 * 4 + 2], w.z, a1);
        a1 = fmaf(sh_dec[k4 * 4 + 3], w.w, a1);
      }
#pragma unroll 4
      for (int k4 = 0; k4 < H_ / 4; ++k4) {
        const float4 w = wh4[k4];
        a2 = fmaf(sh_h[k4 * 4 + 0], w.x, a2);
        a2 = fmaf(sh_h[k4 * 4 + 1], w.y, a2);
        a2 = fmaf(sh_h[k4 * 4 + 2], w.z, a2);
        a2 = fmaf(sh_h[k4 * 4 + 3], w.w, a2);
      }
      sh_gates[j] = __fadd_rn(__fadd_rn(__fadd_rn(a1, b_ih[j]), a2), b_hh[j]);
    }
    __syncthreads();
    // (2) cell update
    if (tid < H_) {
      const float gi = sigmoid_ref(sh_gates[tid]);
      const float gf = sigmoid_ref(sh_gates[H_ + tid]);
      const float gg = tanh_ref(sh_gates[2 * H_ + tid]);
      const float go = sigmoid_ref(sh_gates[3 * H_ + tid]);
      const float cn = __fadd_rn(__fmul_rn(gf, sh_c[tid]), __fmul_rn(gi, gg));
      sh_c[tid] = cn;
      sh_h[tid] = __fmul_rn(go, tanh_ref(cn));
    }
    __syncthreads();
    // (3) pq = [h,cap].W_proj^T + b ; qg = pq.Wq_g^T + bq_g
    if (tid < H_) {
      const float4* wp4 = (const float4*)(W_proj + (size_t)tid * (H_ + CD_));
      float a = 0.0f;
#pragma unroll 4
      for (int k4 = 0; k4 < H_ / 4; ++k4) {
        const float4 w = wp4[k4];
        a = fmaf(sh_h[k4 * 4 + 0], w.x, a);
        a = fmaf(sh_h[k4 * 4 + 1], w.y, a);
        a = fmaf(sh_h[k4 * 4 + 2], w.z, a);
        a = fmaf(sh_h[k4 * 4 + 3], w.w, a);
      }
#pragma unroll
      for (int k4 = 0; k4 < CD_ / 4; ++k4) {
        const float4 w = wp4[H_ / 4 + k4];
        a = fmaf(sh_cap[k4 * 4 + 0], w.x, a);
        a = fmaf(sh_cap[k4 * 4 + 1], w.y, a);
        a = fmaf(sh_cap[k4 * 4 + 2], w.z, a);
        a = fmaf(sh_cap[k4 * 4 + 3], w.w, a);
      }
      sh_pq[tid] = __fadd_rn(a, b_proj[tid]);
    }
    __syncthreads();
    if (tid < H_) {
      const float4* wq4 = (const float4*)(Wq_g + (size_t)tid * H_);
      float a = 0.0f;
#pragma unroll 4
      for (int k4 = 0; k4 < H_ / 4; ++k4) {
        const float4 w = wq4[k4];
        a = fmaf(sh_pq[k4 * 4 + 0], w.x, a);
        a = fmaf(sh_pq[k4 * 4 + 1], w.y, a);
        a = fmaf(sh_pq[k4 * 4 + 2], w.z, a);
        a = fmaf(sh_pq[k4 * 4 + 3], w.w, a);
      }
      sh_q[tid] = __fadd_rn(a, bq_g[tid]);
    }
    __syncthreads();
    // (4) glimpse scores (e_g from LDS, tanhs pipelined in free regs)
    float gl = score_lds(eg_lds, sh_vg, sh_q);
    {
      const float wm = wave_max(gl);
      if (lane == 0) sh_red[wv] = wm;
    }
    __syncthreads();
    {
      const float gmax = fmaxf(fmaxf(sh_red[0], sh_red[1]), fmaxf(sh_red[2], sh_red[3]));
      const float ge = expf(__fsub_rn(gl, gmax));
      const float wsm = wave_sum(ge);
      if (lane == 0) sh_red[4 + wv] = wsm;
      __syncthreads();
      const float gtot = __fadd_rn(__fadd_rn(sh_red[4], sh_red[5]), __fadd_rn(sh_red[6], sh_red[7]));
      sh_gw[tid] = ge / gtot;
    }
    __syncthreads();
    // (5) g_l = sum_s ctx[b,h,s]*gw[s]; ctx streamed from L3 (coalesced,
    // per-half s-ascending), 2x16 register pipeline (phase-local)
    {
      const int hh = tid & 127, half = tid >> 7;
      const size_t stride = (size_t)B_ * H_;
      const float* __restrict__ cb =
          context + (size_t)(half * 128) * stride + (size_t)b * H_ + hh;
      const float* __restrict__ gw = sh_gw + half * 128;
      float A[16], Bv[16];
      float acc = 0.0f;
#pragma unroll
      for (int k = 0; k < 16; ++k) A[k] = cb[(size_t)k * stride];
#pragma unroll
      for (int k = 0; k < 16; ++k) Bv[k] = cb[(size_t)(16 + k) * stride];
#pragma unroll
      for (int gp = 0; gp < 3; ++gp) {
#pragma unroll
        for (int k = 0; k < 16; ++k) acc = fmaf(A[k], gw[(2 * gp) * 16 + k], acc);
#pragma unroll
        for (int k = 0; k < 16; ++k) A[k] = cb[(size_t)((2 * gp + 2) * 16 + k) * stride];
#pragma unroll
        for (int k = 0; k < 16; ++k) acc = fmaf(Bv[k], gw[(2 * gp + 1) * 16 + k], acc);
#pragma unroll
        for (int k = 0; k < 16; ++k) Bv[k] = cb[(size_t)((2 * gp + 3) * 16 + k) * stride];
      }
#pragma unroll
      for (int k = 0; k < 16; ++k) acc = fmaf(A[k], gw[6 * 16 + k], acc);
#pragma unroll
      for (int k = 0; k < 16; ++k) acc = fmaf(Bv[k], gw[7 * 16 + k], acc);
      sh_gates[tid] = acc;  // scratch partials
    }
    __syncthreads();
    if (tid < H_) sh_gl2[tid] = __fadd_rn(sh_gates[tid], sh_gates[tid + 128]);
    __syncthreads();
    // (6) fpq = [g_l,cap].W_proj^T + b ; qp = fpq.Wq_p^T + bq_p
    if (tid < H_) {
      const float4* wp4 = (const float4*)(W_proj + (size_t)tid * (H_ + CD_));
      float a = 0.0f;
#pragma unroll 4
      for (int k4 = 0; k4 < H_ / 4; ++k4) {
        const float4 w = wp4[k4];
        a = fmaf(sh_gl2[k4 * 4 + 0], w.x, a);
        a = fmaf(sh_gl2[k4 * 4 + 1], w.y, a);
        a = fmaf(sh_gl2[k4 * 4 + 2], w.z, a);
        a = fmaf(sh_gl2[k4 * 4 + 3], w.w, a);
      }
#pragma unroll
      for (int k4 = 0; k4 < CD_ / 4; ++k4) {
        const float4 w = wp4[H_ / 4 + k4];
        a = fmaf(sh_cap[k4 * 4 + 0], w.x, a);
        a = fmaf(sh_cap[k4 * 4 + 1], w.y, a);
        a = fmaf(sh_cap[k4 * 4 + 2], w.z, a);
        a = fmaf(sh_cap[k4 * 4 + 3], w.w, a);
      }
      sh_pq[tid] = __fadd_rn(a, b_proj[tid]);
    }
    __syncthreads();
    if (tid < H_) {
      const float4* wq4 = (const float4*)(Wq_p + (size_t)tid * H_);
      float a = 0.0f;
#pragma unroll 4
      for (int k4 = 0; k4 < H_ / 4; ++k4) {
        const float4 w = wq4[k4];
        a = fmaf(sh_pq[k4 * 4 + 0], w.x, a);
        a = fmaf(sh_pq[k4 * 4 + 1], w.y, a);
        a = fmaf(sh_pq[k4 * 4 + 2], w.z, a);
        a = fmaf(sh_pq[k4 * 4 + 3], w.w, a);
      }
      sh_q[tid] = __fadd_rn(a, bq_p[tid]);
    }
    __syncthreads();
    // (7) pointer scores (e_p registers), mask, softmax, gumbel sample
    float z;
    {
      const float a = score_reg(ep, sh_vp, sh_q);
      const float logit = __fmul_rn(C_EXPF, tanh_ref(a));
      const bool selb = (sh_sel[tid >> 5] >> (tid & 31)) & 1u;
      const bool wok = (sh_w[tid] <= sh_rem);
      const bool comb = (!selb) && wok;
      const unsigned long long bal = __ballot(comb);
      if (lane == 0) {
        sh_comb[2 * wv] = (uint32_t)bal;
        sh_comb[2 * wv + 1] = (uint32_t)(bal >> 32);
      }
      const float ml = comb ? logit : NEGF;
      {
        const float wm = wave_max(ml);
        if (lane == 0) sh_red[wv] = wm;
      }
      __syncthreads();
      const float pmax = fmaxf(fmaxf(sh_red[0], sh_red[1]), fmaxf(sh_red[2], sh_red[3]));
      const float pe = expf(__fsub_rn(ml, pmax));
      {
        const float wsm = wave_sum(pe);
        if (lane == 0) sh_red[4 + wv] = wsm;
      }
      __syncthreads();
      const float ptot = __fadd_rn(__fadd_rn(sh_red[4], sh_red[5]), __fadd_rn(sh_red[6], sh_red[7]));
      const float p = pe / ptot;
      __builtin_nontemporal_store(p, &out_probs[((size_t)t * B_ + b) * S_ + tid]);

      uint32_t kk0, kk1;
      threefry2x32(0u, 42u, 0u, (uint32_t)t, kk0, kk1);
      uint32_t bits;
      { uint32_t o0, o1; threefry2x32(kk0, kk1, 0u, (uint32_t)(b * S_ + tid), o0, o1); bits = o0 ^ o1; }
      z = __fadd_rn(logf(__fadd_rn(p, 1e-30f)), gumbel_from_bits(bits));
    }
    // (8) argmax (first max wins)
    {
      float bz = z; int bi = tid;
      for (int off = 32; off > 0; off >>= 1) {
        const float oz = __shfl_xor(bz, off);
        const int oi = __shfl_xor(bi, off);
        if (oz > bz || (oz == bz && oi < bi)) { bz = oz; bi = oi; }
      }
      if (lane == 0) { sh_red[wv] = bz; sh_redi[wv] = bi; }
    }
    __syncthreads();
    if (tid == 0) {
      float bz = sh_red[0]; int bi = sh_redi[0];
      for (int w = 1; w < 4; ++w)
        if (sh_red[w] > bz || (sh_red[w] == bz && sh_redi[w] < bi)) { bz = sh_red[w]; bi = sh_redi[w]; }
      sh_idx = bi;
      __builtin_nontemporal_store((float)bi, &out_sel[(size_t)t * B_ + b]);
      const bool valid = (sh_comb[bi >> 5] >> (bi & 31)) & 1u;
      sh_rem = __fsub_rn(sh_rem, __fmul_rn(sh_w[bi], valid ? 1.0f : 0.0f));
      sh_sel[bi >> 5] |= (1u << (bi & 31));
    }
    __syncthreads();
    if (tid < E_) sh_dec[tid] = emb[((size_t)sh_idx * B_ + b) * E_ + tid];
    __syncthreads();
  }
}

extern "C" void kernel_launch(void* const* d_in, const int* in_sizes, int n_in,
                              void* d_out, int out_size, void* d_ws, size_t ws_size,
                              hipStream_t stream) {
  const float* dec0 = (const float*)d_in[0];
  const float* emb = (const float*)d_in[1];
  const float* h0 = (const float*)d_in[2];
  const float* c0 = (const float*)d_in[3];
  const float* context = (const float*)d_in[4];
  const float* capacity = (const float*)d_in[5];
  const float* weights = (const float*)d_in[7];
  const float* W_ih = (const float*)d_in[8];
  const float* b_ih = (const float*)d_in[9];
  const float* W_hh = (const float*)d_in[10];
  const float* b_hh = (const float*)d_in[11];
  const float* W_cap = (const float*)d_in[12];
  const float* b_cap = (const float*)d_in[13];
  const float* W_proj = (const float*)d_in[14];
  const float* b_proj = (const float*)d_in[15];
  const float* Wq_g = (const float*)d_in[16];
  const float* bq_g = (const float*)d_in[17];
  const float* Wr_g = (const float*)d_in[18];
  const float* br_g = (const float*)d_in[19];
  const float* v_g = (const float*)d_in[20];
  const float* Wq_p = (const float*)d_in[21];
  const float* bq_p = (const float*)d_in[22];
  const float* Wr_p = (const float*)d_in[23];
  const float* br_p = (const float*)d_in[24];
  const float* v_p = (const float*)d_in[25];

  float* e_g = (float*)d_ws;                          // [B,S,H] = 128 MB
  float* e_p = e_g + (size_t)B_ * S_ * H_;            // [B,S,H] = 128 MB
  float* out_probs = (float*)d_out;                   // [S,B,S]
  float* out_sel = out_probs + (size_t)S_ * B_ * S_;  // [S,B]

  precompute_e<<<dim3(B_, S_ / 64), 256, 0, stream>>>(context, Wr_g, br_g, Wr_p,
                                                      br_p, e_g, e_p);
  decoder_main<<<dim3(B_), 256, 0, stream>>>(
      dec0, emb, h0, c0, context, capacity, weights, W_ih, b_ih, W_hh,
      b_hh, W_cap, b_cap, W_proj, b_proj, Wq_g, bq_g, v_g, Wq_p, bq_p, v_p,
      e_g, e_p, out_probs, out_sel);
}

// Round 13
// 47699.905 us; speedup vs baseline: 1.2687x; 1.0205x over previous
//
#include <hip/hip_runtime.h>
#include <stdint.h>
#include <math.h>

#define S_ 256
#define B_ 1024
#define E_ 128
#define H_ 128
#define CD_ 16
#define NEGF (-1.0e9f)
#define C_EXPF 10.0f
#define TINYF 1.17549435e-38f

// ---------------- XLA/Eigen-style float32 tanh (rational 13/6) -------------
__device__ __forceinline__ float tanh_ref(float x) {
  const float kClamp = 7.90531110763549805f;
  float xc = fminf(fmaxf(x, -kClamp), kClamp);
  float x2 = __fmul_rn(xc, xc);
  float p = fmaf(x2, -2.76076847742355e-16f, 2.00018790482477e-13f);
  p = fmaf(x2, p, -8.60467152213735e-11f);
  p = fmaf(x2, p, 5.12229709037114e-08f);
  p = fmaf(x2, p, 1.48572235717979e-05f);
  p = fmaf(x2, p, 6.37261928875436e-04f);
  p = fmaf(x2, p, 4.89352455891786e-03f);
  p = __fmul_rn(xc, p);
  float q = fmaf(x2, 1.19825839466702e-06f, 1.18534705686654e-04f);
  q = fmaf(x2, q, 2.26843463243900e-03f);
  q = fmaf(x2, q, 4.89352518554385e-03f);
  return p / q;
}

__device__ __forceinline__ float sigmoid_ref(float x) {
  return 1.0f / (1.0f + expf(-x));
}

// ---------------- threefry2x32 (jax-exact) ---------------------------------
__device__ __forceinline__ uint32_t rotl32(uint32_t v, uint32_t r) {
  return (v << r) | (v >> (32u - r));
}
__device__ __forceinline__ void threefry2x32(uint32_t k0, uint32_t k1,
                                             uint32_t x0, uint32_t x1,
                                             uint32_t& o0, uint32_t& o1) {
  const uint32_t k2 = k0 ^ k1 ^ 0x1BD11BDAu;
  x0 += k0; x1 += k1;
  x0 += x1; x1 = rotl32(x1, 13); x1 ^= x0;
  x0 += x1; x1 = rotl32(x1, 15); x1 ^= x0;
  x0 += x1; x1 = rotl32(x1, 26); x1 ^= x0;
  x0 += x1; x1 = rotl32(x1,  6); x1 ^= x0;
  x0 += k1; x1 += k2 + 1u;
  x0 += x1; x1 = rotl32(x1, 17); x1 ^= x0;
  x0 += x1; x1 = rotl32(x1, 29); x1 ^= x0;
  x0 += x1; x1 = rotl32(x1, 16); x1 ^= x0;
  x0 += x1; x1 = rotl32(x1, 24); x1 ^= x0;
  x0 += k2; x1 += k0 + 2u;
  x0 += x1; x1 = rotl32(x1, 13); x1 ^= x0;
  x0 += x1; x1 = rotl32(x1, 15); x1 ^= x0;
  x0 += x1; x1 = rotl32(x1, 26); x1 ^= x0;
  x0 += x1; x1 = rotl32(x1,  6); x1 ^= x0;
  x0 += k0; x1 += k1 + 3u;
  x0 += x1; x1 = rotl32(x1, 17); x1 ^= x0;
  x0 += x1; x1 = rotl32(x1, 29); x1 ^= x0;
  x0 += x1; x1 = rotl32(x1, 16); x1 ^= x0;
  x0 += x1; x1 = rotl32(x1, 24); x1 ^= x0;
  x0 += k1; x1 += k2 + 4u;
  x0 += x1; x1 = rotl32(x1, 13); x1 ^= x0;
  x0 += x1; x1 = rotl32(x1, 15); x1 ^= x0;
  x0 += x1; x1 = rotl32(x1, 26); x1 ^= x0;
  x0 += x1; x1 = rotl32(x1,  6); x1 ^= x0;
  x0 += k2; x1 += k0 + 5u;
  o0 = x0; o1 = x1;
}

__device__ __forceinline__ float gumbel_from_bits(uint32_t bits) {
  float f = __uint_as_float((bits >> 9) | 0x3f800000u) - 1.0f;
  f = __fadd_rn(f, TINYF);
  f = fmaxf(f, TINYF);
  return -logf(-logf(f));
}

// ---------------- wave helpers ---------------------------------------------
__device__ __forceinline__ float wave_max(float v) {
  for (int off = 32; off > 0; off >>= 1) v = fmaxf(v, __shfl_xor(v, off));
  return v;
}
__device__ __forceinline__ float wave_sum(float v) {
  for (int off = 32; off > 0; off >>= 1) v = __fadd_rn(v, __shfl_xor(v, off));
  return v;
}

// 64 tanh evals for one half-row (args identical to serial reference)
__device__ __forceinline__ void tanh_half(float* dst, const float4* ehalf,
                                          const float* sq, int h0) {
#pragma unroll
  for (int j = 0; j < 16; ++j) {
    const float4 e = ehalf[j];
    const int h = h0 + j * 4;
    dst[j * 4 + 0] = tanh_ref(__fadd_rn(sq[h + 0], e.x));
    dst[j * 4 + 1] = tanh_ref(__fadd_rn(sq[h + 1], e.y));
    dst[j * 4 + 2] = tanh_ref(__fadd_rn(sq[h + 2], e.z));
    dst[j * 4 + 3] = tanh_ref(__fadd_rn(sq[h + 3], e.w));
  }
}
// fold 64 values in strict h-ascending order, continuing chain from a
__device__ __forceinline__ float fold64(float a, const float* sv, int h0,
                                        const float* tv) {
#pragma unroll
  for (int k = 0; k < 64; ++k) a = fmaf(sv[h0 + k], tv[k], a);
  return a;
}

// ---------------- precompute e_g / e_p: layout [B,S,H] ---------------------
__global__ __launch_bounds__(256) void precompute_e(
    const float* __restrict__ context,  // [S,B,H]
    const float* __restrict__ Wr_g, const float* __restrict__ br_g,
    const float* __restrict__ Wr_p, const float* __restrict__ br_p,
    float* __restrict__ e_g, float* __restrict__ e_p) {
  const int b = blockIdx.x;
  const int s0 = blockIdx.y * 64;
  const int tid = threadIdx.x;
  __shared__ float ctx[64 * 129];
  for (int i = tid; i < 64 * H_; i += 256) {
    const int sl = i >> 7, h = i & 127;
    ctx[sl * 129 + h] = context[((size_t)(s0 + sl) * B_ + b) * H_ + h];
  }
  __syncthreads();
  const int sl = tid & 63, og = tid >> 6;
  for (int o = og; o < H_; o += 4) {
    const float* __restrict__ wg = Wr_g + (size_t)o * H_;
    const float* __restrict__ wp = Wr_p + (size_t)o * H_;
    float ag = 0.0f, ap = 0.0f;
    for (int h = 0; h < H_; ++h) {
      const float cv = ctx[sl * 129 + h];
      ag = fmaf(wg[h], cv, ag);
      ap = fmaf(wp[h], cv, ap);
    }
    ag = __fadd_rn(ag, br_g[o]);
    ap = __fadd_rn(ap, br_p[o]);
    const size_t off = ((size_t)b * S_ + (s0 + sl)) * H_ + o;  // [b][s][h]
    e_g[off] = ag;
    e_p[off] = ap;
  }
}

// ---------------- main: 512 threads per batch row, A/B half-row pairs ------
// __launch_bounds__(512,1): 1 block/CU, 8 waves on 4 SIMDs = 2 waves/SIMD,
// EACH wave gets the full 256-VGPR budget (2x256 = 512-reg file exactly).
// This is the missing config: full e-residency (no spill) AND 2-wave TLP.
__global__ __launch_bounds__(512, 1) void decoder_main(
    const float* __restrict__ dec0, const float* __restrict__ emb,
    const float* __restrict__ h0, const float* __restrict__ c0,
    const float* __restrict__ context, const float* __restrict__ capacity,
    const float* __restrict__ weights,
    const float* __restrict__ W_ih, const float* __restrict__ b_ih,
    const float* __restrict__ W_hh, const float* __restrict__ b_hh,
    const float* __restrict__ W_cap, const float* __restrict__ b_cap,
    const float* __restrict__ W_proj, const float* __restrict__ b_proj,
    const float* __restrict__ Wq_g, const float* __restrict__ bq_g,
    const float* __restrict__ v_g,
    const float* __restrict__ Wq_p, const float* __restrict__ bq_p,
    const float* __restrict__ v_p,
    const float* __restrict__ e_g, const float* __restrict__ e_p,
    float* __restrict__ out_probs, float* __restrict__ out_sel) {
  const int b = blockIdx.x;
  const int tid = threadIdx.x;
  const int lane = tid & 63;
  const int wv = tid >> 6;        // 0..7
  const int isB = tid >> 8;       // 0 = A (h 0..63), 1 = B (h 64..127)
  const int s_own = tid & 255;    // row this thread co-owns

  __shared__ float lds_ctx[S_ * H_];  // 128 KB: ctx slice [s][h]
  __shared__ float sh_h[H_], sh_c[H_], sh_dec[E_];
  __shared__ float sh_pq[H_], sh_q[H_], sh_gl2[H_];
  __shared__ float sh_gates[2 * S_];  // LSTM gates / partial scratch
  __shared__ float sh_gw[S_], sh_w[S_];
  __shared__ float sh_cap[CD_], sh_vg[H_], sh_vp[H_];
  __shared__ uint32_t sh_sel[S_ / 32], sh_comb[S_ / 32];
  __shared__ float sh_red[8];
  __shared__ int sh_redi[8];
  __shared__ float sh_rem;
  __shared__ int sh_idx;

  if (tid < H_) {
    sh_h[tid] = h0[(size_t)b * H_ + tid];
    sh_c[tid] = c0[(size_t)b * H_ + tid];
    sh_dec[tid] = dec0[(size_t)b * E_ + tid];
    sh_vg[tid] = v_g[tid];
    sh_vp[tid] = v_p[tid];
  }
  if (tid < CD_) {
    sh_cap[tid] = __fadd_rn(__fmul_rn(capacity[b], W_cap[tid]), b_cap[tid]);
  }
  if (tid < S_ / 32) sh_sel[tid] = 0u;
  if (tid < S_) sh_w[tid] = weights[(size_t)b * S_ + tid];
  if (tid == 0) sh_rem = capacity[b];

  // one-time: ctx slice -> LDS ([s][h], coalesced float4 loads)
  for (int i = tid; i < S_ * H_ / 4; i += 512) {
    const int s = i >> 5, h4 = i & 31;
    ((float4*)lds_ctx)[i] =
        *(const float4*)(context + ((size_t)s * B_ + b) * H_ + h4 * 4);
  }

  // one-time: this thread's e half-rows -> registers (16+16 float4)
  const float4* __restrict__ eg4 = (const float4*)(e_g + ((size_t)b * S_ + s_own) * H_);
  const float4* __restrict__ ep4 = (const float4*)(e_p + ((size_t)b * S_ + s_own) * H_);
  float4 egh[16], eph[16];
#pragma unroll
  for (int j = 0; j < 16; ++j) egh[j] = eg4[isB * 16 + j];
#pragma unroll
  for (int j = 0; j < 16; ++j) eph[j] = ep4[isB * 16 + j];
  __syncthreads();

  for (int t = 0; t < S_; ++t) {
    // (1) LSTM gates: one row per thread (512 rows), k ascending
    {
      const int j = tid;
      const float4* wi4 = (const float4*)(W_ih + (size_t)j * E_);
      const float4* wh4 = (const float4*)(W_hh + (size_t)j * H_);
      float a1 = 0.0f, a2 = 0.0f;
#pragma unroll 4
      for (int k4 = 0; k4 < E_ / 4; ++k4) {
        const float4 w = wi4[k4];
        a1 = fmaf(sh_dec[k4 * 4 + 0], w.x, a1);
        a1 = fmaf(sh_dec[k4 * 4 + 1], w.y, a1);
        a1 = fmaf(sh_dec[k4 * 4 + 2], w.z, a1);
        a1 = fmaf(sh_dec[k4 * 4 + 3], w.w, a1);
      }
#pragma unroll 4
      for (int k4 = 0; k4 < H_ / 4; ++k4) {
        const float4 w = wh4[k4];
        a2 = fmaf(sh_h[k4 * 4 + 0], w.x, a2);
        a2 = fmaf(sh_h[k4 * 4 + 1], w.y, a2);
        a2 = fmaf(sh_h[k4 * 4 + 2], w.z, a2);
        a2 = fmaf(sh_h[k4 * 4 + 3], w.w, a2);
      }
      sh_gates[j] = __fadd_rn(__fadd_rn(__fadd_rn(a1, b_ih[j]), a2), b_hh[j]);
    }
    __syncthreads();
    // (2) cell update
    if (tid < H_) {
      const float gi = sigmoid_ref(sh_gates[tid]);
      const float gf = sigmoid_ref(sh_gates[H_ + tid]);
      const float gg = tanh_ref(sh_gates[2 * H_ + tid]);
      const float go = sigmoid_ref(sh_gates[3 * H_ + tid]);
      const float cn = __fadd_rn(__fmul_rn(gf, sh_c[tid]), __fmul_rn(gi, gg));
      sh_c[tid] = cn;
      sh_h[tid] = __fmul_rn(go, tanh_ref(cn));
    }
    __syncthreads();
    // (3) pq = [h,cap].W_proj^T + b ; qg = pq.Wq_g^T + bq_g
    if (tid < H_) {
      const float4* wp4 = (const float4*)(W_proj + (size_t)tid * (H_ + CD_));
      float a = 0.0f;
#pragma unroll 4
      for (int k4 = 0; k4 < H_ / 4; ++k4) {
        const float4 w = wp4[k4];
        a = fmaf(sh_h[k4 * 4 + 0], w.x, a);
        a = fmaf(sh_h[k4 * 4 + 1], w.y, a);
        a = fmaf(sh_h[k4 * 4 + 2], w.z, a);
        a = fmaf(sh_h[k4 * 4 + 3], w.w, a);
      }
#pragma unroll
      for (int k4 = 0; k4 < CD_ / 4; ++k4) {
        const float4 w = wp4[H_ / 4 + k4];
        a = fmaf(sh_cap[k4 * 4 + 0], w.x, a);
        a = fmaf(sh_cap[k4 * 4 + 1], w.y, a);
        a = fmaf(sh_cap[k4 * 4 + 2], w.z, a);
        a = fmaf(sh_cap[k4 * 4 + 3], w.w, a);
      }
      sh_pq[tid] = __fadd_rn(a, b_proj[tid]);
    }
    __syncthreads();
    if (tid < H_) {
      const float4* wq4 = (const float4*)(Wq_g + (size_t)tid * H_);
      float a = 0.0f;
#pragma unroll 4
      for (int k4 = 0; k4 < H_ / 4; ++k4) {
        const float4 w = wq4[k4];
        a = fmaf(sh_pq[k4 * 4 + 0], w.x, a);
        a = fmaf(sh_pq[k4 * 4 + 1], w.y, a);
        a = fmaf(sh_pq[k4 * 4 + 2], w.z, a);
        a = fmaf(sh_pq[k4 * 4 + 3], w.w, a);
      }
      sh_q[tid] = __fadd_rn(a, bq_g[tid]);
    }
    __syncthreads();
    // (4) glimpse scores: A+B compute 64 tanh each in parallel; fold is one
    // h-ascending chain (A h0-63 from 0, handoff, B h64-127) — bit-identical
    {
      float tv[64];
      tanh_half(tv, egh, sh_q, isB * 64);
      if (!isB) sh_gates[s_own] = fold64(0.0f, sh_vg, 0, tv);
      __syncthreads();
      float gl = 0.0f, ge = 0.0f;
      if (isB) {
        gl = fold64(sh_gates[s_own], sh_vg, 64, tv);
        const float wm = wave_max(gl);
        if (lane == 0) sh_red[wv - 4] = wm;
      }
      __syncthreads();
      if (isB) {
        const float gmax = fmaxf(fmaxf(sh_red[0], sh_red[1]), fmaxf(sh_red[2], sh_red[3]));
        ge = expf(__fsub_rn(gl, gmax));
        const float wsm = wave_sum(ge);
        if (lane == 0) sh_red[4 + (wv - 4)] = wsm;
      }
      __syncthreads();
      if (isB) {
        const float gtot = __fadd_rn(__fadd_rn(sh_red[4], sh_red[5]), __fadd_rn(sh_red[6], sh_red[7]));
        sh_gw[s_own] = ge / gtot;
      }
    }
    __syncthreads();
    // (5) g_l = sum_s ctx[b,h,s]*gw[s] — A threads, validated 2x128 pattern
    if (!isB) {
      const int hh = tid & 127, half = tid >> 7;
      const float* __restrict__ cl = lds_ctx + (size_t)(half * 128) * H_ + hh;
      const float* __restrict__ gw = sh_gw + half * 128;
      float acc = 0.0f;
#pragma unroll 8
      for (int s = 0; s < 128; ++s) acc = fmaf(cl[(size_t)s * H_], gw[s], acc);
      sh_gates[tid] = acc;  // scratch partials
    }
    __syncthreads();
    if (tid < H_) sh_gl2[tid] = __fadd_rn(sh_gates[tid], sh_gates[tid + 128]);
    __syncthreads();
    // (6) fpq = [g_l,cap].W_proj^T + b ; qp = fpq.Wq_p^T + bq_p
    if (tid < H_) {
      const float4* wp4 = (const float4*)(W_proj + (size_t)tid * (H_ + CD_));
      float a = 0.0f;
#pragma unroll 4
      for (int k4 = 0; k4 < H_ / 4; ++k4) {
        const float4 w = wp4[k4];
        a = fmaf(sh_gl2[k4 * 4 + 0], w.x, a);
        a = fmaf(sh_gl2[k4 * 4 + 1], w.y, a);
        a = fmaf(sh_gl2[k4 * 4 + 2], w.z, a);
        a = fmaf(sh_gl2[k4 * 4 + 3], w.w, a);
      }
#pragma unroll
      for (int k4 = 0; k4 < CD_ / 4; ++k4) {
        const float4 w = wp4[H_ / 4 + k4];
        a = fmaf(sh_cap[k4 * 4 + 0], w.x, a);
        a = fmaf(sh_cap[k4 * 4 + 1], w.y, a);
        a = fmaf(sh_cap[k4 * 4 + 2], w.z, a);
        a = fmaf(sh_cap[k4 * 4 + 3], w.w, a);
      }
      sh_pq[tid] = __fadd_rn(a, b_proj[tid]);
    }
    __syncthreads();
    if (tid < H_) {
      const float4* wq4 = (const float4*)(Wq_p + (size_t)tid * H_);
      float a = 0.0f;
#pragma unroll 4
      for (int k4 = 0; k4 < H_ / 4; ++k4) {
        const float4 w = wq4[k4];
        a = fmaf(sh_pq[k4 * 4 + 0], w.x, a);
        a = fmaf(sh_pq[k4 * 4 + 1], w.y, a);
        a = fmaf(sh_pq[k4 * 4 + 2], w.z, a);
        a = fmaf(sh_pq[k4 * 4 + 3], w.w, a);
      }
      sh_q[tid] = __fadd_rn(a, bq_p[tid]);
    }
    __syncthreads();
    // (7) pointer scores: same A/B split; B finishes logit/softmax/sample
    {
      float tv[64];
      tanh_half(tv, eph, sh_q, isB * 64);
      if (!isB) sh_gates[s_own] = fold64(0.0f, sh_vp, 0, tv);
      __syncthreads();
      float pe = 0.0f, z = 0.0f;
      if (isB) {
        const float a = fold64(sh_gates[s_own], sh_vp, 64, tv);
        const float logit = __fmul_rn(C_EXPF, tanh_ref(a));
        const bool selb = (sh_sel[s_own >> 5] >> (s_own & 31)) & 1u;
        const bool wok = (sh_w[s_own] <= sh_rem);
        const bool comb = (!selb) && wok;
        const unsigned long long bal = __ballot(comb);
        if (lane == 0) {
          sh_comb[2 * (wv - 4)] = (uint32_t)bal;
          sh_comb[2 * (wv - 4) + 1] = (uint32_t)(bal >> 32);
        }
        const float ml = comb ? logit : NEGF;
        const float wm = wave_max(ml);
        if (lane == 0) sh_red[wv - 4] = wm;
        pe = ml;  // hold masked logit across barrier
      }
      __syncthreads();
      if (isB) {
        const float pmax = fmaxf(fmaxf(sh_red[0], sh_red[1]), fmaxf(sh_red[2], sh_red[3]));
        pe = expf(__fsub_rn(pe, pmax));
        const float wsm = wave_sum(pe);
        if (lane == 0) sh_red[4 + (wv - 4)] = wsm;
      }
      __syncthreads();
      if (isB) {
        const float ptot = __fadd_rn(__fadd_rn(sh_red[4], sh_red[5]), __fadd_rn(sh_red[6], sh_red[7]));
        const float p = pe / ptot;
        __builtin_nontemporal_store(p, &out_probs[((size_t)t * B_ + b) * S_ + s_own]);
        uint32_t kk0, kk1;
        threefry2x32(0u, 42u, 0u, (uint32_t)t, kk0, kk1);
        uint32_t bits;
        { uint32_t o0, o1; threefry2x32(kk0, kk1, 0u, (uint32_t)(b * S_ + s_own), o0, o1); bits = o0 ^ o1; }
        z = __fadd_rn(logf(__fadd_rn(p, 1e-30f)), gumbel_from_bits(bits));
        // (8) argmax within wave (first max wins)
        float bz = z; int bi = s_own;
        for (int off = 32; off > 0; off >>= 1) {
          const float oz = __shfl_xor(bz, off);
          const int oi = __shfl_xor(bi, off);
          if (oz > bz || (oz == bz && oi < bi)) { bz = oz; bi = oi; }
        }
        if (lane == 0) { sh_red[wv - 4] = bz; sh_redi[wv - 4] = bi; }
      }
    }
    __syncthreads();
    if (tid == 0) {
      float bz = sh_red[0]; int bi = sh_redi[0];
      for (int w = 1; w < 4; ++w)
        if (sh_red[w] > bz || (sh_red[w] == bz && sh_redi[w] < bi)) { bz = sh_red[w]; bi = sh_redi[w]; }
      sh_idx = bi;
      __builtin_nontemporal_store((float)bi, &out_sel[(size_t)t * B_ + b]);
      const bool valid = (sh_comb[bi >> 5] >> (bi & 31)) & 1u;
      sh_rem = __fsub_rn(sh_rem, __fmul_rn(sh_w[bi], valid ? 1.0f : 0.0f));
      sh_sel[bi >> 5] |= (1u << (bi & 31));
    }
    __syncthreads();
    if (tid < E_) sh_dec[tid] = emb[((size_t)sh_idx * B_ + b) * E_ + tid];
    __syncthreads();
  }
}

extern "C" void kernel_launch(void* const* d_in, const int* in_sizes, int n_in,
                              void* d_out, int out_size, void* d_ws, size_t ws_size,
                              hipStream_t stream) {
  const float* dec0 = (const float*)d_in[0];
  const float* emb = (const float*)d_in[1];
  const float* h0 = (const float*)d_in[2];
  const float* c0 = (const float*)d_in[3];
  const float* context = (const float*)d_in[4];
  const float* capacity = (const float*)d_in[5];
  const float* weights = (const float*)d_in[7];
  const float* W_ih = (const float*)d_in[8];
  const float* b_ih = (const float*)d_in[9];
  const float* W_hh = (const float*)d_in[10];
  const float* b_hh = (const float*)d_in[11];
  const float* W_cap = (const float*)d_in[12];
  const float* b_cap = (const float*)d_in[13];
  const float* W_proj = (const float*)d_in[14];
  const float* b_proj = (const float*)d_in[15];
  const float* Wq_g = (const float*)d_in[16];
  const float* bq_g = (const float*)d_in[17];
  const float* Wr_g = (const float*)d_in[18];
  const float* br_g = (const float*)d_in[19];
  const float* v_g = (const float*)d_in[20];
  const float* Wq_p = (const float*)d_in[21];
  const float* bq_p = (const float*)d_in[22];
  const float* Wr_p = (const float*)d_in[23];
  const float* br_p = (const float*)d_in[24];
  const float* v_p = (const float*)d_in[25];

  float* e_g = (float*)d_ws;                          // [B,S,H] = 128 MB
  float* e_p = e_g + (size_t)B_ * S_ * H_;            // [B,S,H] = 128 MB
  float* out_probs = (float*)d_out;                   // [S,B,S]
  float* out_sel = out_probs + (size_t)S_ * B_ * S_;  // [S,B]

  precompute_e<<<dim3(B_, S_ / 64), 256, 0, stream>>>(context, Wr_g, br_g, Wr_p,
                                                      br_p, e_g, e_p);
  decoder_main<<<dim3(B_), 512, 0, stream>>>(
      dec0, emb, h0, c0, context, capacity, weights, W_ih, b_ih, W_hh,
      b_hh, W_cap, b_cap, W_proj, b_proj, Wq_g, bq_g, v_g, Wq_p, bq_p, v_p,
      e_g, e_p, out_probs, out_sel);
}

// Round 14
// 45028.012 us; speedup vs baseline: 1.3440x; 1.0593x over previous
//
#include <hip/hip_runtime.h>
#include <stdint.h>
#include <math.h>

#define S_ 256
#define B_ 1024
#define E_ 128
#define H_ 128
#define CD_ 16
#define NEGF (-1.0e9f)
#define C_EXPF 10.0f
#define TINYF 1.17549435e-38f

// ---------------- fast tanh: (e^{2x}-1)/(e^{2x}+1) --------------------------
// |abs err| <= ~2e-7 vs true tanh — 10-100x below the demonstrated flip
// tolerance (np-ref uses libm tanh + BLAS order and shows zero flips).
// Clamp at 9.011 (tanh==1.0f beyond) to avoid exp overflow.
__device__ __forceinline__ float tanh_fast(float x) {
  const float xc = fminf(fmaxf(x, -9.010913f), 9.010913f);
  const float e = __expf(__fmul_rn(2.0f, xc));
  return __fdividef(e - 1.0f, e + 1.0f);
}

__device__ __forceinline__ float sigmoid_fast(float x) {
  return __fdividef(1.0f, 1.0f + __expf(-x));
}

// ---------------- threefry2x32 (jax-exact) ---------------------------------
__device__ __forceinline__ uint32_t rotl32(uint32_t v, uint32_t r) {
  return (v << r) | (v >> (32u - r));
}
__device__ __forceinline__ void threefry2x32(uint32_t k0, uint32_t k1,
                                             uint32_t x0, uint32_t x1,
                                             uint32_t& o0, uint32_t& o1) {
  const uint32_t k2 = k0 ^ k1 ^ 0x1BD11BDAu;
  x0 += k0; x1 += k1;
  x0 += x1; x1 = rotl32(x1, 13); x1 ^= x0;
  x0 += x1; x1 = rotl32(x1, 15); x1 ^= x0;
  x0 += x1; x1 = rotl32(x1, 26); x1 ^= x0;
  x0 += x1; x1 = rotl32(x1,  6); x1 ^= x0;
  x0 += k1; x1 += k2 + 1u;
  x0 += x1; x1 = rotl32(x1, 17); x1 ^= x0;
  x0 += x1; x1 = rotl32(x1, 29); x1 ^= x0;
  x0 += x1; x1 = rotl32(x1, 16); x1 ^= x0;
  x0 += x1; x1 = rotl32(x1, 24); x1 ^= x0;
  x0 += k2; x1 += k0 + 2u;
  x0 += x1; x1 = rotl32(x1, 13); x1 ^= x0;
  x0 += x1; x1 = rotl32(x1, 15); x1 ^= x0;
  x0 += x1; x1 = rotl32(x1, 26); x1 ^= x0;
  x0 += x1; x1 = rotl32(x1,  6); x1 ^= x0;
  x0 += k0; x1 += k1 + 3u;
  x0 += x1; x1 = rotl32(x1, 17); x1 ^= x0;
  x0 += x1; x1 = rotl32(x1, 29); x1 ^= x0;
  x0 += x1; x1 = rotl32(x1, 16); x1 ^= x0;
  x0 += x1; x1 = rotl32(x1, 24); x1 ^= x0;
  x0 += k1; x1 += k2 + 4u;
  x0 += x1; x1 = rotl32(x1, 13); x1 ^= x0;
  x0 += x1; x1 = rotl32(x1, 15); x1 ^= x0;
  x0 += x1; x1 = rotl32(x1, 26); x1 ^= x0;
  x0 += x1; x1 = rotl32(x1,  6); x1 ^= x0;
  x0 += k2; x1 += k0 + 5u;
  o0 = x0; o1 = x1;
}

__device__ __forceinline__ float gumbel_from_bits(uint32_t bits) {
  float f = __uint_as_float((bits >> 9) | 0x3f800000u) - 1.0f;
  f = __fadd_rn(f, TINYF);
  f = fmaxf(f, TINYF);
  return -logf(-logf(f));
}

// ---------------- wave helpers ---------------------------------------------
__device__ __forceinline__ float wave_max(float v) {
  for (int off = 32; off > 0; off >>= 1) v = fmaxf(v, __shfl_xor(v, off));
  return v;
}
__device__ __forceinline__ float wave_sum(float v) {
  for (int off = 32; off > 0; off >>= 1) v = __fadd_rn(v, __shfl_xor(v, off));
  return v;
}

// 4 score terms, h ascending — same fold order as always
__device__ __forceinline__ void acc4(float& a, const float* sv, const float* sq,
                                     int h, float4 e) {
  a = fmaf(sv[h + 0], tanh_fast(__fadd_rn(sq[h + 0], e.x)), a);
  a = fmaf(sv[h + 1], tanh_fast(__fadd_rn(sq[h + 1], e.y)), a);
  a = fmaf(sv[h + 2], tanh_fast(__fadd_rn(sq[h + 2], e.z)), a);
  a = fmaf(sv[h + 3], tanh_fast(__fadd_rn(sq[h + 3], e.w)), a);
}

// score over a REGISTER-resident e-row (32 float4, static idx)
__device__ __forceinline__ float score_reg(const float4* ereg,
                                           const float* sv, const float* sq) {
  float a = 0.0f;
#pragma unroll
  for (int k4 = 0; k4 < 32; ++k4) acc4(a, sv, sq, k4 * 4, ereg[k4]);
  return a;
}

// ---------------- precompute e_g / e_p: layout [B,S,H] ---------------------
__global__ __launch_bounds__(256) void precompute_e(
    const float* __restrict__ context,  // [S,B,H]
    const float* __restrict__ Wr_g, const float* __restrict__ br_g,
    const float* __restrict__ Wr_p, const float* __restrict__ br_p,
    float* __restrict__ e_g, float* __restrict__ e_p) {
  const int b = blockIdx.x;
  const int s0 = blockIdx.y * 64;
  const int tid = threadIdx.x;
  __shared__ float ctx[64 * 129];
  for (int i = tid; i < 64 * H_; i += 256) {
    const int sl = i >> 7, h = i & 127;
    ctx[sl * 129 + h] = context[((size_t)(s0 + sl) * B_ + b) * H_ + h];
  }
  __syncthreads();
  const int sl = tid & 63, og = tid >> 6;
  for (int o = og; o < H_; o += 4) {
    const float* __restrict__ wg = Wr_g + (size_t)o * H_;
    const float* __restrict__ wp = Wr_p + (size_t)o * H_;
    float ag = 0.0f, ap = 0.0f;
    for (int h = 0; h < H_; ++h) {
      const float cv = ctx[sl * 129 + h];
      ag = fmaf(wg[h], cv, ag);
      ap = fmaf(wp[h], cv, ap);
    }
    ag = __fadd_rn(ag, br_g[o]);
    ap = __fadd_rn(ap, br_p[o]);
    const size_t off = ((size_t)b * S_ + (s0 + sl)) * H_ + o;  // [b][s][h]
    e_g[off] = ag;
    e_p[off] = ap;
  }
}

// ---------------- main: one block per batch row, 256 steps -----------------
// R8 structure: e_g AND e_p rows (s==tid) register-resident; ctx slice
// LDS-resident; ZERO steady-state HBM reads. Fast nonlinearities.
__global__ __launch_bounds__(256, 1) void decoder_main(
    const float* __restrict__ dec0, const float* __restrict__ emb,
    const float* __restrict__ h0, const float* __restrict__ c0,
    const float* __restrict__ context, const float* __restrict__ capacity,
    const float* __restrict__ weights,
    const float* __restrict__ W_ih, const float* __restrict__ b_ih,
    const float* __restrict__ W_hh, const float* __restrict__ b_hh,
    const float* __restrict__ W_cap, const float* __restrict__ b_cap,
    const float* __restrict__ W_proj, const float* __restrict__ b_proj,
    const float* __restrict__ Wq_g, const float* __restrict__ bq_g,
    const float* __restrict__ v_g,
    const float* __restrict__ Wq_p, const float* __restrict__ bq_p,
    const float* __restrict__ v_p,
    const float* __restrict__ e_g, const float* __restrict__ e_p,
    float* __restrict__ out_probs, float* __restrict__ out_sel) {
  const int b = blockIdx.x;
  const int tid = threadIdx.x;
  const int lane = tid & 63;
  const int wv = tid >> 6;

  __shared__ float lds_ctx[S_ * H_];  // 128 KB: ctx slice [s][h]
  __shared__ float sh_h[H_], sh_c[H_], sh_dec[E_];
  __shared__ float sh_pq[H_], sh_q[H_], sh_gl2[H_];
  __shared__ float sh_gates[4 * H_];
  __shared__ float sh_gw[S_], sh_w[S_];
  __shared__ float sh_cap[CD_], sh_vg[H_], sh_vp[H_];
  __shared__ uint32_t sh_sel[S_ / 32], sh_comb[S_ / 32];
  __shared__ float sh_red[8];
  __shared__ int sh_redi[8];
  __shared__ float sh_rem;
  __shared__ int sh_idx;

  if (tid < H_) {
    sh_h[tid] = h0[(size_t)b * H_ + tid];
    sh_c[tid] = c0[(size_t)b * H_ + tid];
    sh_dec[tid] = dec0[(size_t)b * E_ + tid];
    sh_vg[tid] = v_g[tid];
    sh_vp[tid] = v_p[tid];
  }
  if (tid < CD_) {
    sh_cap[tid] = __fadd_rn(__fmul_rn(capacity[b], W_cap[tid]), b_cap[tid]);
  }
  if (tid < S_ / 32) sh_sel[tid] = 0u;
  sh_w[tid] = weights[(size_t)b * S_ + tid];
  if (tid == 0) sh_rem = capacity[b];

  // one-time: ctx slice -> LDS ([s][h], coalesced float4 loads)
  for (int i = tid; i < S_ * H_ / 4; i += 256) {
    const int s = i >> 5, h4 = i & 31;
    ((float4*)lds_ctx)[i] =
        *(const float4*)(context + ((size_t)s * B_ + b) * H_ + h4 * 4);
  }

  // one-time: this thread's e rows (s == tid) -> registers for all steps
  const float4* __restrict__ eg_row4 = (const float4*)(e_g + ((size_t)b * S_ + tid) * H_);
  const float4* __restrict__ ep_row4 = (const float4*)(e_p + ((size_t)b * S_ + tid) * H_);
  float4 eg[32], ep[32];
#pragma unroll
  for (int k4 = 0; k4 < 32; ++k4) eg[k4] = eg_row4[k4];
#pragma unroll
  for (int k4 = 0; k4 < 32; ++k4) ep[k4] = ep_row4[k4];
  __syncthreads();

  for (int t = 0; t < S_; ++t) {
    // (1) LSTM gates, float4-vectorized rows, k ascending
#pragma unroll
    for (int jj = 0; jj < 2; ++jj) {
      const int j = tid + jj * 256;
      const float4* wi4 = (const float4*)(W_ih + (size_t)j * E_);
      const float4* wh4 = (const float4*)(W_hh + (size_t)j * H_);
      float a1 = 0.0f, a2 = 0.0f;
#pragma unroll 4
      for (int k4 = 0; k4 < E_ / 4; ++k4) {
        const float4 w = wi4[k4];
        a1 = fmaf(sh_dec[k4 * 4 + 0], w.x, a1);
        a1 = fmaf(sh_dec[k4 * 4 + 1], w.y, a1);
        a1 = fmaf(sh_dec[k4 * 4 + 2], w.z, a1);
        a1 = fmaf(sh_dec[k4 * 4 + 3], w.w, a1);
      }
#pragma unroll 4
      for (int k4 = 0; k4 < H_ / 4; ++k4) {
        const float4 w = wh4[k4];
        a2 = fmaf(sh_h[k4 * 4 + 0], w.x, a2);
        a2 = fmaf(sh_h[k4 * 4 + 1], w.y, a2);
        a2 = fmaf(sh_h[k4 * 4 + 2], w.z, a2);
        a2 = fmaf(sh_h[k4 * 4 + 3], w.w, a2);
      }
      sh_gates[j] = __fadd_rn(__fadd_rn(__fadd_rn(a1, b_ih[j]), a2), b_hh[j]);
    }
    __syncthreads();
    // (2) cell update
    if (tid < H_) {
      const float gi = sigmoid_fast(sh_gates[tid]);
      const float gf = sigmoid_fast(sh_gates[H_ + tid]);
      const float gg = tanh_fast(sh_gates[2 * H_ + tid]);
      const float go = sigmoid_fast(sh_gates[3 * H_ + tid]);
      const float cn = __fadd_rn(__fmul_rn(gf, sh_c[tid]), __fmul_rn(gi, gg));
      sh_c[tid] = cn;
      sh_h[tid] = __fmul_rn(go, tanh_fast(cn));
    }
    __syncthreads();
    // (3) pq = [h,cap].W_proj^T + b ; qg = pq.Wq_g^T + bq_g
    if (tid < H_) {
      const float4* wp4 = (const float4*)(W_proj + (size_t)tid * (H_ + CD_));
      float a = 0.0f;
#pragma unroll 4
      for (int k4 = 0; k4 < H_ / 4; ++k4) {
        const float4 w = wp4[k4];
        a = fmaf(sh_h[k4 * 4 + 0], w.x, a);
        a = fmaf(sh_h[k4 * 4 + 1], w.y, a);
        a = fmaf(sh_h[k4 * 4 + 2], w.z, a);
        a = fmaf(sh_h[k4 * 4 + 3], w.w, a);
      }
#pragma unroll
      for (int k4 = 0; k4 < CD_ / 4; ++k4) {
        const float4 w = wp4[H_ / 4 + k4];
        a = fmaf(sh_cap[k4 * 4 + 0], w.x, a);
        a = fmaf(sh_cap[k4 * 4 + 1], w.y, a);
        a = fmaf(sh_cap[k4 * 4 + 2], w.z, a);
        a = fmaf(sh_cap[k4 * 4 + 3], w.w, a);
      }
      sh_pq[tid] = __fadd_rn(a, b_proj[tid]);
    }
    __syncthreads();
    if (tid < H_) {
      const float4* wq4 = (const float4*)(Wq_g + (size_t)tid * H_);
      float a = 0.0f;
#pragma unroll 4
      for (int k4 = 0; k4 < H_ / 4; ++k4) {
        const float4 w = wq4[k4];
        a = fmaf(sh_pq[k4 * 4 + 0], w.x, a);
        a = fmaf(sh_pq[k4 * 4 + 1], w.y, a);
        a = fmaf(sh_pq[k4 * 4 + 2], w.z, a);
        a = fmaf(sh_pq[k4 * 4 + 3], w.w, a);
      }
      sh_q[tid] = __fadd_rn(a, bq_g[tid]);
    }
    __syncthreads();
    // (4) glimpse scores (pure VALU, e_g registers) + softmax
    float gl = score_reg(eg, sh_vg, sh_q);
    {
      const float wm = wave_max(gl);
      if (lane == 0) sh_red[wv] = wm;
    }
    __syncthreads();
    {
      const float gmax = fmaxf(fmaxf(sh_red[0], sh_red[1]), fmaxf(sh_red[2], sh_red[3]));
      const float ge = __expf(__fsub_rn(gl, gmax));
      const float wsm = wave_sum(ge);
      if (lane == 0) sh_red[4 + wv] = wsm;
      __syncthreads();
      const float gtot = __fadd_rn(__fadd_rn(sh_red[4], sh_red[5]), __fadd_rn(sh_red[6], sh_red[7]));
      sh_gw[tid] = __fdividef(ge, gtot);
    }
    __syncthreads();
    // (5) g_l = sum_s ctx[b,h,s]*gw[s] — ctx from LDS, per-half s-ascending
    {
      const int hh = tid & 127, half = tid >> 7;
      const float* __restrict__ cl = lds_ctx + (size_t)(half * 128) * H_ + hh;
      const float* __restrict__ gw = sh_gw + half * 128;
      float acc = 0.0f;
#pragma unroll 8
      for (int s = 0; s < 128; ++s) acc = fmaf(cl[(size_t)s * H_], gw[s], acc);
      sh_gates[tid] = acc;  // scratch partials
    }
    __syncthreads();
    if (tid < H_) sh_gl2[tid] = __fadd_rn(sh_gates[tid], sh_gates[tid + 128]);
    __syncthreads();
    // (6) fpq = [g_l,cap].W_proj^T + b ; qp = fpq.Wq_p^T + bq_p
    if (tid < H_) {
      const float4* wp4 = (const float4*)(W_proj + (size_t)tid * (H_ + CD_));
      float a = 0.0f;
#pragma unroll 4
      for (int k4 = 0; k4 < H_ / 4; ++k4) {
        const float4 w = wp4[k4];
        a = fmaf(sh_gl2[k4 * 4 + 0], w.x, a);
        a = fmaf(sh_gl2[k4 * 4 + 1], w.y, a);
        a = fmaf(sh_gl2[k4 * 4 + 2], w.z, a);
        a = fmaf(sh_gl2[k4 * 4 + 3], w.w, a);
      }
#pragma unroll
      for (int k4 = 0; k4 < CD_ / 4; ++k4) {
        const float4 w = wp4[H_ / 4 + k4];
        a = fmaf(sh_cap[k4 * 4 + 0], w.x, a);
        a = fmaf(sh_cap[k4 * 4 + 1], w.y, a);
        a = fmaf(sh_cap[k4 * 4 + 2], w.z, a);
        a = fmaf(sh_cap[k4 * 4 + 3], w.w, a);
      }
      sh_pq[tid] = __fadd_rn(a, b_proj[tid]);
    }
    __syncthreads();
    if (tid < H_) {
      const float4* wq4 = (const float4*)(Wq_p + (size_t)tid * H_);
      float a = 0.0f;
#pragma unroll 4
      for (int k4 = 0; k4 < H_ / 4; ++k4) {
        const float4 w = wq4[k4];
        a = fmaf(sh_pq[k4 * 4 + 0], w.x, a);
        a = fmaf(sh_pq[k4 * 4 + 1], w.y, a);
        a = fmaf(sh_pq[k4 * 4 + 2], w.z, a);
        a = fmaf(sh_pq[k4 * 4 + 3], w.w, a);
      }
      sh_q[tid] = __fadd_rn(a, bq_p[tid]);
    }
    __syncthreads();
    // (7) pointer scores (pure VALU, e_p registers), mask, softmax, sample
    float z;
    {
      const float a = score_reg(ep, sh_vp, sh_q);
      const float logit = __fmul_rn(C_EXPF, tanh_fast(a));
      const bool selb = (sh_sel[tid >> 5] >> (tid & 31)) & 1u;
      const bool wok = (sh_w[tid] <= sh_rem);
      const bool comb = (!selb) && wok;
      const unsigned long long bal = __ballot(comb);
      if (lane == 0) {
        sh_comb[2 * wv] = (uint32_t)bal;
        sh_comb[2 * wv + 1] = (uint32_t)(bal >> 32);
      }
      const float ml = comb ? logit : NEGF;
      {
        const float wm = wave_max(ml);
        if (lane == 0) sh_red[wv] = wm;
      }
      __syncthreads();
      const float pmax = fmaxf(fmaxf(sh_red[0], sh_red[1]), fmaxf(sh_red[2], sh_red[3]));
      const float pe = __expf(__fsub_rn(ml, pmax));
      {
        const float wsm = wave_sum(pe);
        if (lane == 0) sh_red[4 + wv] = wsm;
      }
      __syncthreads();
      const float ptot = __fadd_rn(__fadd_rn(sh_red[4], sh_red[5]), __fadd_rn(sh_red[6], sh_red[7]));
      const float p = __fdividef(pe, ptot);
      __builtin_nontemporal_store(p, &out_probs[((size_t)t * B_ + b) * S_ + tid]);

      uint32_t kk0, kk1;
      threefry2x32(0u, 42u, 0u, (uint32_t)t, kk0, kk1);
      uint32_t bits;
      { uint32_t o0, o1; threefry2x32(kk0, kk1, 0u, (uint32_t)(b * S_ + tid), o0, o1); bits = o0 ^ o1; }
      z = __fadd_rn(logf(__fadd_rn(p, 1e-30f)), gumbel_from_bits(bits));
    }
    // (8) argmax (first max wins)
    {
      float bz = z; int bi = tid;
      for (int off = 32; off > 0; off >>= 1) {
        const float oz = __shfl_xor(bz, off);
        const int oi = __shfl_xor(bi, off);
        if (oz > bz || (oz == bz && oi < bi)) { bz = oz; bi = oi; }
      }
      if (lane == 0) { sh_red[wv] = bz; sh_redi[wv] = bi; }
    }
    __syncthreads();
    if (tid == 0) {
      float bz = sh_red[0]; int bi = sh_redi[0];
      for (int w = 1; w < 4; ++w)
        if (sh_red[w] > bz || (sh_red[w] == bz && sh_redi[w] < bi)) { bz = sh_red[w]; bi = sh_redi[w]; }
      sh_idx = bi;
      __builtin_nontemporal_store((float)bi, &out_sel[(size_t)t * B_ + b]);
      const bool valid = (sh_comb[bi >> 5] >> (bi & 31)) & 1u;
      sh_rem = __fsub_rn(sh_rem, __fmul_rn(sh_w[bi], valid ? 1.0f : 0.0f));
      sh_sel[bi >> 5] |= (1u << (bi & 31));
    }
    __syncthreads();
    if (tid < E_) sh_dec[tid] = emb[((size_t)sh_idx * B_ + b) * E_ + tid];
    __syncthreads();
  }
}

extern "C" void kernel_launch(void* const* d_in, const int* in_sizes, int n_in,
                              void* d_out, int out_size, void* d_ws, size_t ws_size,
                              hipStream_t stream) {
  const float* dec0 = (const float*)d_in[0];
  const float* emb = (const float*)d_in[1];
  const float* h0 = (const float*)d_in[2];
  const float* c0 = (const float*)d_in[3];
  const float* context = (const float*)d_in[4];
  const float* capacity = (const float*)d_in[5];
  const float* weights = (const float*)d_in[7];
  const float* W_ih = (const float*)d_in[8];
  const float* b_ih = (const float*)d_in[9];
  const float* W_hh = (const float*)d_in[10];
  const float* b_hh = (const float*)d_in[11];
  const float* W_cap = (const float*)d_in[12];
  const float* b_cap = (const float*)d_in[13];
  const float* W_proj = (const float*)d_in[14];
  const float* b_proj = (const float*)d_in[15];
  const float* Wq_g = (const float*)d_in[16];
  const float* bq_g = (const float*)d_in[17];
  const float* Wr_g = (const float*)d_in[18];
  const float* br_g = (const float*)d_in[19];
  const float* v_g = (const float*)d_in[20];
  const float* Wq_p = (const float*)d_in[21];
  const float* bq_p = (const float*)d_in[22];
  const float* Wr_p = (const float*)d_in[23];
  const float* br_p = (const float*)d_in[24];
  const float* v_p = (const float*)d_in[25];

  float* e_g = (float*)d_ws;                          // [B,S,H] = 128 MB
  float* e_p = e_g + (size_t)B_ * S_ * H_;            // [B,S,H] = 128 MB
  float* out_probs = (float*)d_out;                   // [S,B,S]
  float* out_sel = out_probs + (size_t)S_ * B_ * S_;  // [S,B]

  precompute_e<<<dim3(B_, S_ / 64), 256, 0, stream>>>(context, Wr_g, br_g, Wr_p,
                                                      br_p, e_g, e_p);
  decoder_main<<<dim3(B_), 256, 0, stream>>>(
      dec0, emb, h0, c0, context, capacity, weights, W_ih, b_ih, W_hh,
      b_hh, W_cap, b_cap, W_proj, b_proj, Wq_g, bq_g, v_g, Wq_p, bq_p, v_p,
      e_g, e_p, out_probs, out_sel);
}